// Round 2
// baseline (347.522 us; speedup 1.0000x reference)
//
#include <hip/hip_runtime.h>

#define NV   150000
#define CIN  32
#define COUT 64
#define KK   27
#define EPSF 1e-5f
#define NCOPY 8   // striped atomic copies for stats

__device__ __forceinline__ void red4(float4& a, int off) {
    a.x += __shfl_xor(a.x, off);
    a.y += __shfl_xor(a.y, off);
    a.z += __shfl_xor(a.z, off);
    a.w += __shfl_xor(a.w, off);
}

// ---------------------------------------------------------------------------
// K1: submanifold conv, 4 threads per voxel (16 channels each) + fused
// BN-stat accumulation (block reduce -> striped global atomics).
// ---------------------------------------------------------------------------
__global__ __launch_bounds__(256) void k_conv(
    const float* __restrict__ feat,    // [NV, CIN]
    const float* __restrict__ weight,  // [27, CIN, COUT]
    const int*   __restrict__ nbr,     // [27, NV]
    float*       __restrict__ out,     // [NV, COUT] (pre-BN conv result)
    float*       __restrict__ gstats)  // [NCOPY][128] atomic sums
{
    const int t = blockIdx.x * 256 + threadIdx.x;
    const int v = t >> 2;              // voxel
    const int g = threadIdx.x & 3;     // channel group: channels [g*16, g*16+16)
    const bool valid = (v < NV);

    float4 a0 = {0,0,0,0}, a1 = {0,0,0,0}, a2 = {0,0,0,0}, a3 = {0,0,0,0};

    // weight as float4: index = k*512 + c*16 + g*4 + j
    const float4* wbase = (const float4*)weight + g * 4;

#pragma unroll 1
    for (int k = 0; k < KK; ++k) {
        const int idx = valid ? nbr[k * NV + v] : -1;
        if (idx >= 0) {
            const float4* fr = (const float4*)(feat + (long)idx * CIN);
            float4 f[8];
#pragma unroll
            for (int q = 0; q < 8; ++q) f[q] = fr[q];
            const float4* wk = wbase + k * 512;
#pragma unroll
            for (int c = 0; c < CIN; ++c) {
                const float4 fq = f[c >> 2];
                const int m = c & 3;
                const float fv = (m == 0) ? fq.x : (m == 1) ? fq.y : (m == 2) ? fq.z : fq.w;
                const float4* w = wk + c * 16;
                float4 w0 = w[0], w1 = w[1], w2 = w[2], w3 = w[3];
                a0.x += fv * w0.x; a0.y += fv * w0.y; a0.z += fv * w0.z; a0.w += fv * w0.w;
                a1.x += fv * w1.x; a1.y += fv * w1.y; a1.z += fv * w1.z; a1.w += fv * w1.w;
                a2.x += fv * w2.x; a2.y += fv * w2.y; a2.z += fv * w2.z; a2.w += fv * w2.w;
                a3.x += fv * w3.x; a3.y += fv * w3.y; a3.z += fv * w3.z; a3.w += fv * w3.w;
            }
        }
    }

    // ---- write conv output ----
    if (valid) {
        float4* o = (float4*)(out + (long)v * COUT) + g * 4;
        o[0] = a0; o[1] = a1; o[2] = a2; o[3] = a3;
    }

    // ---- fused BN statistics ----
    // per-thread sum / sumsq over its 16 channels (invalid threads hold 0)
    float4 s0 = a0, s1 = a1, s2 = a2, s3 = a3;
    float4 q0, q1, q2, q3;
    q0.x = a0.x * a0.x; q0.y = a0.y * a0.y; q0.z = a0.z * a0.z; q0.w = a0.w * a0.w;
    q1.x = a1.x * a1.x; q1.y = a1.y * a1.y; q1.z = a1.z * a1.z; q1.w = a1.w * a1.w;
    q2.x = a2.x * a2.x; q2.y = a2.y * a2.y; q2.z = a2.z * a2.z; q2.w = a2.w * a2.w;
    q3.x = a3.x * a3.x; q3.y = a3.y * a3.y; q3.z = a3.z * a3.z; q3.w = a3.w * a3.w;

    // butterfly across the 16 lanes sharing this channel group (strides 4..32)
#pragma unroll
    for (int off = 4; off < 64; off <<= 1) {
        red4(s0, off); red4(s1, off); red4(s2, off); red4(s3, off);
        red4(q0, off); red4(q1, off); red4(q2, off); red4(q3, off);
    }

    __shared__ float lsum[4][64];
    __shared__ float lsq[4][64];
    const int lane = threadIdx.x & 63;
    const int wav  = threadIdx.x >> 6;
    if (lane < 4) {
        // this lane's g == lane; it holds the wave-wide sums for its 16 channels
        float4* ds = (float4*)&lsum[wav][lane * 16];
        float4* dq = (float4*)&lsq[wav][lane * 16];
        ds[0] = s0; ds[1] = s1; ds[2] = s2; ds[3] = s3;
        dq[0] = q0; dq[1] = q1; dq[2] = q2; dq[3] = q3;
    }
    __syncthreads();

    if (threadIdx.x < 64) {
        const int ch = threadIdx.x;
        float S = lsum[0][ch] + lsum[1][ch] + lsum[2][ch] + lsum[3][ch];
        float Q = lsq[0][ch] + lsq[1][ch] + lsq[2][ch] + lsq[3][ch];
        float* dst = gstats + (blockIdx.x & (NCOPY - 1)) * 128;
        atomicAdd(dst + ch, S);
        atomicAdd(dst + 64 + ch, Q);
    }
}

// ---------------------------------------------------------------------------
// K2: reduce the striped stat copies -> scale/shift.
// ---------------------------------------------------------------------------
__global__ __launch_bounds__(64) void k_final(
    const float* __restrict__ gstats,  // [NCOPY][128]
    const float* __restrict__ gamma,
    const float* __restrict__ beta,
    float*       __restrict__ stats)   // [128]: 64 scale, 64 shift
{
    const int ch = threadIdx.x;
    float s = 0.f, q = 0.f;
#pragma unroll
    for (int cp = 0; cp < NCOPY; ++cp) {
        s += gstats[cp * 128 + ch];
        q += gstats[cp * 128 + 64 + ch];
    }
    const float inv_n = 1.f / (float)NV;
    const float mean = s * inv_n;
    float var = q * inv_n - mean * mean;
    var = fmaxf(var, 0.f);
    const float rstd = rsqrtf(var + EPSF);
    const float scale = gamma[ch] * rstd;
    const float shift = beta[ch] - mean * scale;
    stats[ch] = scale;
    stats[64 + ch] = shift;
}

// ---------------------------------------------------------------------------
// K3: in-place affine + ReLU. 2,400,000 float4 chunks = 9375 x 256.
// ---------------------------------------------------------------------------
__global__ __launch_bounds__(256) void k_norm(
    float* __restrict__ out,
    const float* __restrict__ stats)
{
    __shared__ float4 sc[16];
    __shared__ float4 sh[16];
    if (threadIdx.x < 16) {
        sc[threadIdx.x] = ((const float4*)stats)[threadIdx.x];
        sh[threadIdx.x] = ((const float4*)(stats + 64))[threadIdx.x];
    }
    __syncthreads();

    const long i = (long)blockIdx.x * 256 + threadIdx.x;  // chunk id
    const int  g = threadIdx.x & 15;
    float4 v = ((const float4*)out)[i];
    const float4 S = sc[g];
    const float4 H = sh[g];
    v.x = fmaxf(v.x * S.x + H.x, 0.f);
    v.y = fmaxf(v.y * S.y + H.y, 0.f);
    v.z = fmaxf(v.z * S.z + H.z, 0.f);
    v.w = fmaxf(v.w * S.w + H.w, 0.f);
    ((float4*)out)[i] = v;
}

// ---------------------------------------------------------------------------
extern "C" void kernel_launch(void* const* d_in, const int* in_sizes, int n_in,
                              void* d_out, int out_size, void* d_ws, size_t ws_size,
                              hipStream_t stream) {
    const float* feat   = (const float*)d_in[0];
    const float* weight = (const float*)d_in[1];
    const float* gamma  = (const float*)d_in[2];
    const float* beta   = (const float*)d_in[3];
    const int*   nbr    = (const int*)d_in[4];
    float* out = (float*)d_out;

    float* gstats = (float*)d_ws;              // NCOPY*128 floats
    float* stats  = gstats + NCOPY * 128;      // 128 floats

    hipMemsetAsync(d_ws, 0, NCOPY * 128 * sizeof(float), stream);

    k_conv<<<(NV * 4 + 255) / 256, 256, 0, stream>>>(feat, weight, nbr, out, gstats);
    k_final<<<1, 64, 0, stream>>>(gstats, gamma, beta, stats);
    k_norm<<<(NV * COUT / 4) / 256, 256, 0, stream>>>(out, stats);
}

// Round 3
// 202.191 us; speedup vs baseline: 1.7188x; 1.7188x over previous
//
#include <hip/hip_runtime.h>

#define NV   150000
#define CIN  32
#define COUT 64
#define EPSF 1e-5f
#define NCOPY 8

// d_ws layout (bytes):
//   [0,4)        uint pair counter
//   [1024,5120)  float gstats[NCOPY][128]   (atomic stripes: 64 sum + 64 sumsq)
//   [5120,5632)  float stats[128]           (64 scale, 64 shift)
//   [8192,...)   int2 pairs[cap]            (x = v | k<<20, y = idx)

__device__ __forceinline__ float elem8(const float4* f, int c) {
    const float4 q = f[c >> 2];
    const int m = c & 3;
    return (m == 0) ? q.x : (m == 1) ? q.y : (m == 2) ? q.z : q.w;
}

// ---------------------------------------------------------------------------
// K1: dense center-tap GEMM (W13 staged in LDS) + fused rulebook compaction.
// 2 threads per voxel; thread g scans taps {g?14..26:0..12} and computes
// output channels [g*32, g*32+32).
// ---------------------------------------------------------------------------
__global__ __launch_bounds__(256) void k_center(
    const float* __restrict__ feat,    // [NV, CIN]
    const float* __restrict__ weight,  // [27, CIN, COUT]
    const int*   __restrict__ nbr,     // [27, NV]
    float*       __restrict__ out,     // [NV, COUT]
    int2*        __restrict__ pairs,
    unsigned int* __restrict__ counter,
    int cap)
{
    __shared__ float4 w13[512];  // 2048 floats = W[13][32][64]
    {
        const float4* wsrc = (const float4*)(weight + 13 * CIN * COUT);
        w13[threadIdx.x * 2]     = wsrc[threadIdx.x * 2];
        w13[threadIdx.x * 2 + 1] = wsrc[threadIdx.x * 2 + 1];
    }
    __syncthreads();

    const int t = blockIdx.x * 256 + threadIdx.x;
    const int v = t >> 1;
    const int g = t & 1;
    const bool valid = (v < NV);
    const int lane = threadIdx.x & 63;

    // ---- scan 13 off-center taps: independent unrolled loads, no branches ----
    const int kbase = g ? 14 : 0;
    const int* nb = nbr + kbase * NV + (valid ? v : 0);
    int idxs[13];
#pragma unroll
    for (int i = 0; i < 13; ++i) idxs[i] = valid ? nb[i * NV] : -1;

    int cnt = 0;
#pragma unroll
    for (int i = 0; i < 13; ++i) cnt += (idxs[i] >= 0) ? 1 : 0;

    // wave-wide inclusive prefix sum of cnt
    int x = cnt;
#pragma unroll
    for (int off = 1; off < 64; off <<= 1) {
        int y = __shfl_up(x, off);
        if (lane >= off) x += y;
    }
    const int total = __shfl(x, 63);
    int base = 0;
    if (lane == 63 && total > 0) base = (int)atomicAdd(counter, (unsigned)total);
    base = __shfl(base, 63);

    int pos = base + (x - cnt);  // exclusive prefix
#pragma unroll
    for (int i = 0; i < 13; ++i) {
        if (idxs[i] >= 0) {
            if (pos < cap) pairs[pos] = make_int2(v | ((kbase + i) << 20), idxs[i]);
            ++pos;
        }
    }

    // ---- center GEMM: out[v][g*32 .. g*32+31] = feat[v] @ W13[:, g-half] ----
    float4 f[8];
    const float4* fr = (const float4*)(feat + (long)(valid ? v : 0) * CIN);
#pragma unroll
    for (int q = 0; q < 8; ++q) f[q] = fr[q];

    float4 acc[8];
#pragma unroll
    for (int j = 0; j < 8; ++j) acc[j] = make_float4(0.f, 0.f, 0.f, 0.f);

    const float4* wl = w13 + g * 8;  // row c: w13[c*16 + g*8 + j]
#pragma unroll
    for (int c = 0; c < CIN; ++c) {
        const float fv = elem8(f, c);
        const float4* w = wl + c * 16;
#pragma unroll
        for (int j = 0; j < 8; ++j) {
            const float4 ww = w[j];
            acc[j].x += fv * ww.x;
            acc[j].y += fv * ww.y;
            acc[j].z += fv * ww.z;
            acc[j].w += fv * ww.w;
        }
    }

    if (valid) {
        float4* o = (float4*)(out + (long)v * COUT + g * 32);
#pragma unroll
        for (int j = 0; j < 8; ++j) o[j] = acc[j];
    }
}

// ---------------------------------------------------------------------------
// K2: scatter the sparse pairs. One wave per pair; lane j owns out channel j.
// k is wave-uniform -> coalesced weight rows + broadcast features.
// ---------------------------------------------------------------------------
__global__ __launch_bounds__(256) void k_scatter(
    const float* __restrict__ feat,
    const float* __restrict__ weight,
    const int2*  __restrict__ pairs,
    const unsigned int* __restrict__ counter,
    int cap,
    float* __restrict__ out)
{
    const int lane = threadIdx.x & 63;
    const int wid  = blockIdx.x * 4 + (threadIdx.x >> 6);
    const int nw   = gridDim.x * 4;
    const int count = (int)min(*counter, (unsigned int)cap);

    for (int p = wid; p < count; p += nw) {
        const int2 pr = pairs[p];
        const int v   = pr.x & 0xFFFFF;
        const int k   = pr.x >> 20;
        const int idx = pr.y;

        const float f = feat[(long)idx * CIN + (lane & 31)];
        const float* wk = weight + (long)k * CIN * COUT + lane;

        float acc = 0.f;
#pragma unroll
        for (int c = 0; c < CIN; ++c) {
            const float fc = __shfl(f, c);
            acc += fc * wk[c * COUT];
        }
        atomicAdd(out + (long)v * COUT + lane, acc);
    }
}

// ---------------------------------------------------------------------------
// K3: BN statistics over final out [NV,64] -> striped atomic sums.
// ---------------------------------------------------------------------------
__global__ __launch_bounds__(256) void k_stats(
    const float* __restrict__ out,
    float*       __restrict__ gstats)  // [NCOPY][128]
{
    const long total4 = (long)NV * COUT / 4;   // 2,400,000
    const int  tid    = blockIdx.x * 256 + threadIdx.x;
    const int  stride = gridDim.x * 256;       // multiple of 16

    float4 s = make_float4(0.f, 0.f, 0.f, 0.f);
    float4 q = make_float4(0.f, 0.f, 0.f, 0.f);
    const float4* o4 = (const float4*)out;
    for (long i = tid; i < total4; i += stride) {
        const float4 w = o4[i];
        s.x += w.x; s.y += w.y; s.z += w.z; s.w += w.w;
        q.x += w.x * w.x; q.y += w.y * w.y; q.z += w.z * w.z; q.w += w.w * w.w;
    }

    __shared__ float4 ls[256];
    __shared__ float4 lq[256];
    ls[threadIdx.x] = s;
    lq[threadIdx.x] = q;
    __syncthreads();

    if (threadIdx.x < 16) {
        float4 S = make_float4(0.f, 0.f, 0.f, 0.f);
        float4 Q = make_float4(0.f, 0.f, 0.f, 0.f);
        for (int t2 = threadIdx.x; t2 < 256; t2 += 16) {
            const float4 a = ls[t2];
            const float4 b = lq[t2];
            S.x += a.x; S.y += a.y; S.z += a.z; S.w += a.w;
            Q.x += b.x; Q.y += b.y; Q.z += b.z; Q.w += b.w;
        }
        float* dst = gstats + (blockIdx.x & (NCOPY - 1)) * 128 + threadIdx.x * 4;
        atomicAdd(dst + 0, S.x); atomicAdd(dst + 1, S.y);
        atomicAdd(dst + 2, S.z); atomicAdd(dst + 3, S.w);
        atomicAdd(dst + 64, Q.x); atomicAdd(dst + 65, Q.y);
        atomicAdd(dst + 66, Q.z); atomicAdd(dst + 67, Q.w);
    }
}

// ---------------------------------------------------------------------------
// K4: reduce stripes -> scale/shift.
// ---------------------------------------------------------------------------
__global__ __launch_bounds__(64) void k_final(
    const float* __restrict__ gstats,
    const float* __restrict__ gamma,
    const float* __restrict__ beta,
    float*       __restrict__ stats)
{
    const int ch = threadIdx.x;
    float s = 0.f, q = 0.f;
#pragma unroll
    for (int cp = 0; cp < NCOPY; ++cp) {
        s += gstats[cp * 128 + ch];
        q += gstats[cp * 128 + 64 + ch];
    }
    const float inv_n = 1.f / (float)NV;
    const float mean = s * inv_n;
    float var = q * inv_n - mean * mean;
    var = fmaxf(var, 0.f);
    const float rstd = rsqrtf(var + EPSF);
    const float scale = gamma[ch] * rstd;
    const float shift = beta[ch] - mean * scale;
    stats[ch] = scale;
    stats[64 + ch] = shift;
}

// ---------------------------------------------------------------------------
// K5: in-place affine + ReLU. 2,400,000 float4 chunks = 9375 x 256.
// ---------------------------------------------------------------------------
__global__ __launch_bounds__(256) void k_norm(
    float* __restrict__ out,
    const float* __restrict__ stats)
{
    __shared__ float4 sc[16];
    __shared__ float4 sh[16];
    if (threadIdx.x < 16) {
        sc[threadIdx.x] = ((const float4*)stats)[threadIdx.x];
        sh[threadIdx.x] = ((const float4*)(stats + 64))[threadIdx.x];
    }
    __syncthreads();

    const long i = (long)blockIdx.x * 256 + threadIdx.x;
    const int  g = threadIdx.x & 15;
    float4 v = ((const float4*)out)[i];
    const float4 S = sc[g];
    const float4 H = sh[g];
    v.x = fmaxf(v.x * S.x + H.x, 0.f);
    v.y = fmaxf(v.y * S.y + H.y, 0.f);
    v.z = fmaxf(v.z * S.z + H.z, 0.f);
    v.w = fmaxf(v.w * S.w + H.w, 0.f);
    ((float4*)out)[i] = v;
}

// ---------------------------------------------------------------------------
extern "C" void kernel_launch(void* const* d_in, const int* in_sizes, int n_in,
                              void* d_out, int out_size, void* d_ws, size_t ws_size,
                              hipStream_t stream) {
    const float* feat   = (const float*)d_in[0];
    const float* weight = (const float*)d_in[1];
    const float* gamma  = (const float*)d_in[2];
    const float* beta   = (const float*)d_in[3];
    const int*   nbr    = (const int*)d_in[4];
    float* out = (float*)d_out;

    char* ws = (char*)d_ws;
    unsigned int* counter = (unsigned int*)ws;
    float* gstats = (float*)(ws + 1024);
    float* stats  = (float*)(ws + 5120);
    int2*  pairs  = (int2*)(ws + 8192);
    const int cap = (int)((ws_size - 8192) / sizeof(int2));

    hipMemsetAsync(d_ws, 0, 5120, stream);

    k_center<<<(NV * 2 + 255) / 256, 256, 0, stream>>>(feat, weight, nbr, out,
                                                       pairs, counter, cap);
    k_scatter<<<1024, 256, 0, stream>>>(feat, weight, pairs, counter, cap, out);
    k_stats<<<512, 256, 0, stream>>>(out, gstats);
    k_final<<<1, 64, 0, stream>>>(gstats, gamma, beta, stats);
    k_norm<<<(NV * COUT / 4) / 256, 256, 0, stream>>>(out, stats);
}